// Round 1
// baseline (518.126 us; speedup 1.0000x reference)
//
#include <hip/hip_runtime.h>

// ---------------------------------------------------------------------------
// Problem: h = relu(x + noise); BN1d(train, eps=0.8); z = hn @ W^T + b
// x: [8192, 4096] f32, W: [4096, 4096] f32, out: [8192, 4096] f32
// ---------------------------------------------------------------------------

#define B_ROWS 8192
#define C_CH   4096
#define N_OUT  4096

// ---------------------- compile-time noise table --------------------------
// Faithful constexpr port of Random + PoolRandom (seed=123, n=4096, *1e-9).
struct alignas(16) NoiseTable { float v[C_CH]; };

constexpr NoiseTable make_noise() {
    unsigned s = 123u;
    unsigned pool[C_CH] = {};
    for (int i = 0; i < C_CH; ++i) { s = 65539u * s + 1u; pool[i] = s; }
    int nxt = C_CH - 1;
    NoiseTable t{};
    for (int i = 0; i < C_CH; ++i) {
        nxt = (int)(pool[nxt] % (unsigned)C_CH);
        t.v[i] = (float)((double)pool[nxt] * 1e-9);
        s = 65539u * s + 1u;
        pool[nxt] = s;
    }
    return t;
}

__device__ constexpr NoiseTable NOISE = make_noise();

// ---------------------- helpers -------------------------------------------
__device__ __forceinline__ unsigned short f2bf(float f) {
    unsigned u = __builtin_bit_cast(unsigned, f);
    unsigned r = (u + 0x7FFFu + ((u >> 16) & 1u)) >> 16;   // RNE
    return (unsigned short)r;
}

typedef __attribute__((ext_vector_type(8))) short bf16x8;
typedef __attribute__((ext_vector_type(4))) float f32x4;

__device__ __forceinline__ void gload16(const void* g, void* l) {
    __builtin_amdgcn_global_load_lds(
        (const __attribute__((address_space(1))) void*)g,
        (__attribute__((address_space(3))) void*)l, 16, 0, 0);
}

// ---------------------- 1) BN stats: per-block partial sums ----------------
// 512 blocks x 16 rows each; thread t owns channels {g*1024 + 4t .. +3}.
__global__ __launch_bounds__(256) void stats_kernel(const float* __restrict__ x,
                                                    float* __restrict__ psum,
                                                    float* __restrict__ psumsq) {
    const int t = threadIdx.x;
    const int b = blockIdx.x;

    float4 nv[4];
    #pragma unroll
    for (int g = 0; g < 4; ++g)
        nv[g] = *reinterpret_cast<const float4*>(&NOISE.v[g * 1024 + 4 * t]);

    float4 s[4], q[4];
    #pragma unroll
    for (int g = 0; g < 4; ++g) { s[g] = make_float4(0,0,0,0); q[g] = make_float4(0,0,0,0); }

    const int row0 = b * 16;
    for (int r = 0; r < 16; ++r) {
        const float* xr = x + (size_t)(row0 + r) * C_CH;
        #pragma unroll
        for (int g = 0; g < 4; ++g) {
            float4 v = *reinterpret_cast<const float4*>(&xr[g * 1024 + 4 * t]);
            float h0 = fmaxf(v.x + nv[g].x, 0.f);
            float h1 = fmaxf(v.y + nv[g].y, 0.f);
            float h2 = fmaxf(v.z + nv[g].z, 0.f);
            float h3 = fmaxf(v.w + nv[g].w, 0.f);
            s[g].x += h0; s[g].y += h1; s[g].z += h2; s[g].w += h3;
            q[g].x += h0*h0; q[g].y += h1*h1; q[g].z += h2*h2; q[g].w += h3*h3;
        }
    }
    #pragma unroll
    for (int g = 0; g < 4; ++g) {
        *reinterpret_cast<float4*>(&psum  [(size_t)b * C_CH + g * 1024 + 4 * t]) = s[g];
        *reinterpret_cast<float4*>(&psumsq[(size_t)b * C_CH + g * 1024 + 4 * t]) = q[g];
    }
}

// ---------------------- 2) finalize: scale/shift per channel ---------------
__global__ __launch_bounds__(256) void finalize_kernel(const float* __restrict__ psum,
                                                       const float* __restrict__ psumsq,
                                                       const float* __restrict__ gamma,
                                                       const float* __restrict__ beta,
                                                       float* __restrict__ scale,
                                                       float* __restrict__ shift) {
    const int c = blockIdx.x * 256 + threadIdx.x;
    float s = 0.f, q = 0.f;
    for (int bk = 0; bk < 512; ++bk) {
        s += psum  [(size_t)bk * C_CH + c];
        q += psumsq[(size_t)bk * C_CH + c];
    }
    const float inv = 1.f / (float)B_ROWS;
    const float mean = s * inv;
    const float var  = fmaxf(q * inv - mean * mean, 0.f);
    const float sc   = gamma[c] / sqrtf(var + 0.8f);
    scale[c] = sc;
    shift[c] = beta[c] - mean * sc;
}

// ---------------------- 3) A conversion: hn in bf16 ------------------------
__global__ __launch_bounds__(256) void convA_kernel(const float* __restrict__ x,
                                                    const float* __restrict__ scale,
                                                    const float* __restrict__ shift,
                                                    unsigned short* __restrict__ out) {
    const size_t total4 = (size_t)B_ROWS * C_CH / 4;
    for (size_t i = (size_t)blockIdx.x * 256 + threadIdx.x; i < total4;
         i += (size_t)gridDim.x * 256) {
        const size_t e = i * 4;
        const int c = (int)(e & (C_CH - 1));
        float4 v  = *reinterpret_cast<const float4*>(&x[e]);
        float4 nv = *reinterpret_cast<const float4*>(&NOISE.v[c]);
        float4 sc = *reinterpret_cast<const float4*>(&scale[c]);
        float4 sh = *reinterpret_cast<const float4*>(&shift[c]);
        ushort4 o;
        o.x = f2bf(fmaxf(v.x + nv.x, 0.f) * sc.x + sh.x);
        o.y = f2bf(fmaxf(v.y + nv.y, 0.f) * sc.y + sh.y);
        o.z = f2bf(fmaxf(v.z + nv.z, 0.f) * sc.z + sh.z);
        o.w = f2bf(fmaxf(v.w + nv.w, 0.f) * sc.w + sh.w);
        *reinterpret_cast<ushort4*>(&out[e]) = o;
    }
}

// ---------------------- 4) W conversion to bf16 ----------------------------
__global__ __launch_bounds__(256) void convW_kernel(const float* __restrict__ W,
                                                    unsigned short* __restrict__ out) {
    const size_t total4 = (size_t)N_OUT * C_CH / 4;
    for (size_t i = (size_t)blockIdx.x * 256 + threadIdx.x; i < total4;
         i += (size_t)gridDim.x * 256) {
        const size_t e = i * 4;
        float4 v = *reinterpret_cast<const float4*>(&W[e]);
        ushort4 o;
        o.x = f2bf(v.x); o.y = f2bf(v.y); o.z = f2bf(v.z); o.w = f2bf(v.w);
        *reinterpret_cast<ushort4*>(&out[e]) = o;
    }
}

// ---------------------- 5) GEMM: C = A(bf16) * B(bf16)^T + bias ------------
// m97 structure: 128x128 tile, BK=32, 4 waves (2x2), 64x64 per wave,
// global_load_lds width-16 staging, 2-barrier K-loop, 16x16x32 bf16 MFMA.
#define TM 128
#define TN 128
#define TK 32

__global__ __launch_bounds__(256) void gemm_bt_kernel(const unsigned short* __restrict__ A,
                                                      const unsigned short* __restrict__ B,
                                                      const float* __restrict__ bias,
                                                      float* __restrict__ C,
                                                      int M, int N, int K) {
    __shared__ unsigned short As[TM * TK];
    __shared__ unsigned short Bs[TN * TK];

    // XCD-bijective swizzle (nwg % 8 == 0)
    const int nwg = gridDim.x;
    const int cpx = nwg >> 3;
    int wg = blockIdx.x;
    wg = (wg & 7) * cpx + (wg >> 3);

    const int nbx = N / TN;
    const int bx = wg % nbx;
    const int by = wg / nbx;
    const int row0 = by * TM;
    const int col0 = bx * TN;

    const int t    = threadIdx.x;
    const int lane = t & 63;
    const int wid  = t >> 6;
    const int wr   = wid >> 1;        // wave row (0..1) -> 64-row band
    const int wc   = wid & 1;         // wave col (0..1) -> 64-col band
    const int l15  = lane & 15;
    const int lk8  = (lane >> 4) * 8;

    // staging: thread t loads 8 bf16 (16B); 4 chunks (A lo/hi, B lo/hi)
    const int srow = t >> 2;          // 0..63
    const int skk  = (t & 3) * 8;     // 0,8,16,24
    const unsigned short* gA0 = A + (size_t)(row0 +      srow) * K + skk;
    const unsigned short* gA1 = A + (size_t)(row0 + 64 + srow) * K + skk;
    const unsigned short* gB0 = B + (size_t)(col0 +      srow) * K + skk;
    const unsigned short* gB1 = B + (size_t)(col0 + 64 + srow) * K + skk;
    unsigned short* lA0 = &As[wid * 512];
    unsigned short* lA1 = &As[2048 + wid * 512];
    unsigned short* lB0 = &Bs[wid * 512];
    unsigned short* lB1 = &Bs[2048 + wid * 512];

    const int aoff = (wr * 64 + l15) * TK + lk8;
    const int boff = (wc * 64 + l15) * TK + lk8;

    f32x4 acc[4][4];
    #pragma unroll
    for (int m = 0; m < 4; ++m)
        #pragma unroll
        for (int n = 0; n < 4; ++n)
            acc[m][n] = (f32x4){0.f, 0.f, 0.f, 0.f};

    for (int k0 = 0; k0 < K; k0 += TK) {
        gload16(gA0, lA0); gload16(gA1, lA1);
        gload16(gB0, lB0); gload16(gB1, lB1);
        gA0 += TK; gA1 += TK; gB0 += TK; gB1 += TK;
        __syncthreads();   // drains vmcnt(0): staged tile visible to all waves

        bf16x8 af[4], bfr[4];
        #pragma unroll
        for (int m = 0; m < 4; ++m)
            af[m] = *reinterpret_cast<const bf16x8*>(&As[aoff + m * 16 * TK]);
        #pragma unroll
        for (int n = 0; n < 4; ++n)
            bfr[n] = *reinterpret_cast<const bf16x8*>(&Bs[boff + n * 16 * TK]);

        #pragma unroll
        for (int m = 0; m < 4; ++m)
            #pragma unroll
            for (int n = 0; n < 4; ++n)
                acc[m][n] = __builtin_amdgcn_mfma_f32_16x16x32_bf16(
                    af[m], bfr[n], acc[m][n], 0, 0, 0);

        __syncthreads();   // all reads done before next stage overwrites LDS
    }

    // epilogue: C/D layout col = lane&15, row = (lane>>4)*4 + j
    #pragma unroll
    for (int n = 0; n < 4; ++n) {
        const int c = col0 + wc * 64 + n * 16 + l15;
        const float bv = bias[c];
        #pragma unroll
        for (int m = 0; m < 4; ++m) {
            const int r0 = row0 + wr * 64 + m * 16 + (lane >> 4) * 4;
            #pragma unroll
            for (int j = 0; j < 4; ++j)
                C[(size_t)(r0 + j) * N + c] = acc[m][n][j] + bv;
        }
    }
}

// ---------------------- launch --------------------------------------------
extern "C" void kernel_launch(void* const* d_in, const int* in_sizes, int n_in,
                              void* d_out, int out_size, void* d_ws, size_t ws_size,
                              hipStream_t stream) {
    const float* x     = (const float*)d_in[0];
    const float* gamma = (const float*)d_in[1];
    const float* beta  = (const float*)d_in[2];
    const float* W     = (const float*)d_in[3];
    const float* b     = (const float*)d_in[4];
    float* out = (float*)d_out;

    char* ws = (char*)d_ws;
    unsigned short* Abf = (unsigned short*)(ws);                       // 64 MiB
    unsigned short* Wbf = (unsigned short*)(ws + 67108864);            // 32 MiB
    float* psum   = (float*)(ws + 100663296);                          // 8 MiB
    float* psumsq = (float*)(ws + 100663296 + 8388608);                // 8 MiB
    float* scale  = (float*)(ws + 100663296 + 16777216);               // 16 KiB
    float* shift  = (float*)(ws + 100663296 + 16777216 + 16384);       // 16 KiB

    hipLaunchKernelGGL(stats_kernel,    dim3(512),  dim3(256), 0, stream, x, psum, psumsq);
    hipLaunchKernelGGL(finalize_kernel, dim3(16),   dim3(256), 0, stream,
                       psum, psumsq, gamma, beta, scale, shift);
    hipLaunchKernelGGL(convA_kernel,    dim3(2048), dim3(256), 0, stream, x, scale, shift, Abf);
    hipLaunchKernelGGL(convW_kernel,    dim3(2048), dim3(256), 0, stream, W, Wbf);
    hipLaunchKernelGGL(gemm_bt_kernel,  dim3(2048), dim3(256), 0, stream,
                       Abf, Wbf, b, out, B_ROWS, N_OUT, C_CH);
}

// Round 2
// 410.217 us; speedup vs baseline: 1.2631x; 1.2631x over previous
//
#include <hip/hip_runtime.h>

// ---------------------------------------------------------------------------
// Problem: h = relu(x + noise); BN1d(train, eps=0.8); z = hn @ W^T + b
// x: [8192, 4096] f32, W: [4096, 4096] f32, out: [8192, 4096] f32
// ---------------------------------------------------------------------------

#define B_ROWS 8192
#define C_CH   4096
#define N_OUT  4096

// ---------------------- compile-time noise table --------------------------
struct alignas(16) NoiseTable { float v[C_CH]; };

constexpr NoiseTable make_noise() {
    unsigned s = 123u;
    unsigned pool[C_CH] = {};
    for (int i = 0; i < C_CH; ++i) { s = 65539u * s + 1u; pool[i] = s; }
    int nxt = C_CH - 1;
    NoiseTable t{};
    for (int i = 0; i < C_CH; ++i) {
        nxt = (int)(pool[nxt] % (unsigned)C_CH);
        t.v[i] = (float)((double)pool[nxt] * 1e-9);
        s = 65539u * s + 1u;
        pool[nxt] = s;
    }
    return t;
}

__device__ constexpr NoiseTable NOISE = make_noise();

// ---------------------- helpers -------------------------------------------
__device__ __forceinline__ unsigned short f2bf(float f) {
    unsigned u = __builtin_bit_cast(unsigned, f);
    unsigned r = (u + 0x7FFFu + ((u >> 16) & 1u)) >> 16;   // RNE
    return (unsigned short)r;
}

typedef __attribute__((ext_vector_type(8))) short bf16x8;
typedef __attribute__((ext_vector_type(4))) float f32x4;

__device__ __forceinline__ void gload16(const void* g, void* l) {
    __builtin_amdgcn_global_load_lds(
        (const __attribute__((address_space(1))) void*)g,
        (__attribute__((address_space(3))) void*)l, 16, 0, 0);
}

#define BARRIER()  do { __builtin_amdgcn_s_barrier(); asm volatile("" ::: "memory"); } while (0)
#define LGKM0()    do { asm volatile("s_waitcnt lgkmcnt(0)" ::: "memory"); \
                        __builtin_amdgcn_sched_barrier(0); } while (0)

// ---------------------- 1) BN stats: per-block partial sums ----------------
__global__ __launch_bounds__(256) void stats_kernel(const float* __restrict__ x,
                                                    float* __restrict__ psum,
                                                    float* __restrict__ psumsq) {
    const int t = threadIdx.x;
    const int b = blockIdx.x;

    float4 nv[4];
    #pragma unroll
    for (int g = 0; g < 4; ++g)
        nv[g] = *reinterpret_cast<const float4*>(&NOISE.v[g * 1024 + 4 * t]);

    float4 s[4], q[4];
    #pragma unroll
    for (int g = 0; g < 4; ++g) { s[g] = make_float4(0,0,0,0); q[g] = make_float4(0,0,0,0); }

    const int row0 = b * 16;
    for (int r = 0; r < 16; ++r) {
        const float* xr = x + (size_t)(row0 + r) * C_CH;
        #pragma unroll
        for (int g = 0; g < 4; ++g) {
            float4 v = *reinterpret_cast<const float4*>(&xr[g * 1024 + 4 * t]);
            float h0 = fmaxf(v.x + nv[g].x, 0.f);
            float h1 = fmaxf(v.y + nv[g].y, 0.f);
            float h2 = fmaxf(v.z + nv[g].z, 0.f);
            float h3 = fmaxf(v.w + nv[g].w, 0.f);
            s[g].x += h0; s[g].y += h1; s[g].z += h2; s[g].w += h3;
            q[g].x += h0*h0; q[g].y += h1*h1; q[g].z += h2*h2; q[g].w += h3*h3;
        }
    }
    #pragma unroll
    for (int g = 0; g < 4; ++g) {
        *reinterpret_cast<float4*>(&psum  [(size_t)b * C_CH + g * 1024 + 4 * t]) = s[g];
        *reinterpret_cast<float4*>(&psumsq[(size_t)b * C_CH + g * 1024 + 4 * t]) = q[g];
    }
}

// ---------------------- 2) finalize: scale/shift per channel ---------------
__global__ __launch_bounds__(256) void finalize_kernel(const float* __restrict__ psum,
                                                       const float* __restrict__ psumsq,
                                                       const float* __restrict__ gamma,
                                                       const float* __restrict__ beta,
                                                       float* __restrict__ scale,
                                                       float* __restrict__ shift) {
    const int c = blockIdx.x * 256 + threadIdx.x;
    float s = 0.f, q = 0.f;
    for (int bk = 0; bk < 512; ++bk) {
        s += psum  [(size_t)bk * C_CH + c];
        q += psumsq[(size_t)bk * C_CH + c];
    }
    const float inv = 1.f / (float)B_ROWS;
    const float mean = s * inv;
    const float var  = fmaxf(q * inv - mean * mean, 0.f);
    const float sc   = gamma[c] / sqrtf(var + 0.8f);
    scale[c] = sc;
    shift[c] = beta[c] - mean * sc;
}

// ---------------------- 3) A conversion: hn in bf16 ------------------------
__global__ __launch_bounds__(256) void convA_kernel(const float* __restrict__ x,
                                                    const float* __restrict__ scale,
                                                    const float* __restrict__ shift,
                                                    unsigned short* __restrict__ out) {
    const size_t total4 = (size_t)B_ROWS * C_CH / 4;
    for (size_t i = (size_t)blockIdx.x * 256 + threadIdx.x; i < total4;
         i += (size_t)gridDim.x * 256) {
        const size_t e = i * 4;
        const int c = (int)(e & (C_CH - 1));
        float4 v  = *reinterpret_cast<const float4*>(&x[e]);
        float4 nv = *reinterpret_cast<const float4*>(&NOISE.v[c]);
        float4 sc = *reinterpret_cast<const float4*>(&scale[c]);
        float4 sh = *reinterpret_cast<const float4*>(&shift[c]);
        ushort4 o;
        o.x = f2bf(fmaxf(v.x + nv.x, 0.f) * sc.x + sh.x);
        o.y = f2bf(fmaxf(v.y + nv.y, 0.f) * sc.y + sh.y);
        o.z = f2bf(fmaxf(v.z + nv.z, 0.f) * sc.z + sh.z);
        o.w = f2bf(fmaxf(v.w + nv.w, 0.f) * sc.w + sh.w);
        *reinterpret_cast<ushort4*>(&out[e]) = o;
    }
}

// ---------------------- 4) W conversion to bf16 ----------------------------
__global__ __launch_bounds__(256) void convW_kernel(const float* __restrict__ W,
                                                    unsigned short* __restrict__ out) {
    const size_t total4 = (size_t)N_OUT * C_CH / 4;
    for (size_t i = (size_t)blockIdx.x * 256 + threadIdx.x; i < total4;
         i += (size_t)gridDim.x * 256) {
        const size_t e = i * 4;
        float4 v = *reinterpret_cast<const float4*>(&W[e]);
        ushort4 o;
        o.x = f2bf(v.x); o.y = f2bf(v.y); o.z = f2bf(v.z); o.w = f2bf(v.w);
        *reinterpret_cast<ushort4*>(&out[e]) = o;
    }
}

// ---------------------- 5) GEMM 256x256x64, 8 waves, counted vmcnt ---------
// LDS per buffer (65536 B): A tile [256 rows][64 k] bf16 at +0 (rows 0-127 =
// half 0, 128-255 = half 1, 16384 B each), B tile at +32768. Within a row
// (8 x 16B slots) the stored slot = logical_slot ^ (row & 7)  (T2 swizzle).
// global_load_lds writes linearly; the global SOURCE is pre-swizzled with the
// same involution, which reduces to slot = (lane&7) ^ (lane>>3).

template<int MH, int NH>
__device__ __forceinline__ void quad_mfma(bf16x8 (&af)[4][2], bf16x8 (&bf)[4][2],
                                          f32x4 (&acc)[8][4]) {
    #pragma unroll
    for (int s = 0; s < 2; ++s)
        #pragma unroll
        for (int m = 0; m < 4; ++m)
            #pragma unroll
            for (int n = 0; n < 2; ++n)
                acc[MH * 4 + m][NH * 2 + n] = __builtin_amdgcn_mfma_f32_16x16x32_bf16(
                    af[m][s], bf[NH * 2 + n][s], acc[MH * 4 + m][NH * 2 + n], 0, 0, 0);
}

template<bool STG>
__device__ __forceinline__ void tile_step(
    char* lds, const int bc, const int bn,
    const char*& pA0, const char*& pA1, const char*& pA2, const char*& pA3,
    const char*& pB0, const char*& pB1, const char*& pB2, const char*& pB3,
    const int dstw, const int aoff0, const int aoff1,
    const int boff0, const int boff1,
    f32x4 (&acc)[8][4]) {

    bf16x8 af[4][2], bf[4][2];

    // ---- phase 0: stage next tile (8 gloads), counted wait, quad(0,0) ----
    if (STG) {
        gload16(pA0, lds + bn +     0 + dstw);
        gload16(pA1, lds + bn +  8192 + dstw);
        gload16(pA2, lds + bn + 16384 + dstw);
        gload16(pA3, lds + bn + 24576 + dstw);
        gload16(pB0, lds + bn + 32768 + dstw);
        gload16(pB1, lds + bn + 40960 + dstw);
        gload16(pB2, lds + bn + 49152 + dstw);
        gload16(pB3, lds + bn + 57344 + dstw);
        pA0 += 128; pA1 += 128; pA2 += 128; pA3 += 128;
        pB0 += 128; pB1 += 128; pB2 += 128; pB3 += 128;
        asm volatile("s_waitcnt vmcnt(8)" ::: "memory");   // current tile landed
    } else {
        asm volatile("s_waitcnt vmcnt(0)" ::: "memory");   // final drain
    }
    BARRIER();                                             // block-wide visibility
    __builtin_amdgcn_sched_barrier(0);
    #pragma unroll
    for (int m = 0; m < 4; ++m) {
        af[m][0] = *reinterpret_cast<const bf16x8*>(lds + bc + aoff0 + m * 2048);
        af[m][1] = *reinterpret_cast<const bf16x8*>(lds + bc + aoff1 + m * 2048);
    }
    #pragma unroll
    for (int n = 0; n < 2; ++n) {
        bf[n][0] = *reinterpret_cast<const bf16x8*>(lds + bc + boff0 + n * 2048);
        bf[n][1] = *reinterpret_cast<const bf16x8*>(lds + bc + boff1 + n * 2048);
    }
    BARRIER(); LGKM0();
    __builtin_amdgcn_s_setprio(1);
    quad_mfma<0, 0>(af, bf, acc);
    __builtin_amdgcn_s_setprio(0);

    // ---- phase 1: read B n2-3, quad(0,1) ----
    BARRIER();
    #pragma unroll
    for (int n = 2; n < 4; ++n) {
        bf[n][0] = *reinterpret_cast<const bf16x8*>(lds + bc + boff0 + n * 2048);
        bf[n][1] = *reinterpret_cast<const bf16x8*>(lds + bc + boff1 + n * 2048);
    }
    BARRIER(); LGKM0();
    __builtin_amdgcn_s_setprio(1);
    quad_mfma<0, 1>(af, bf, acc);
    __builtin_amdgcn_s_setprio(0);

    // ---- phase 2: read A m4-7, quad(1,1) ----
    BARRIER();
    #pragma unroll
    for (int m = 0; m < 4; ++m) {
        af[m][0] = *reinterpret_cast<const bf16x8*>(lds + bc + aoff0 + (m + 4) * 2048);
        af[m][1] = *reinterpret_cast<const bf16x8*>(lds + bc + aoff1 + (m + 4) * 2048);
    }
    BARRIER(); LGKM0();
    __builtin_amdgcn_s_setprio(1);
    quad_mfma<1, 1>(af, bf, acc);
    __builtin_amdgcn_s_setprio(0);

    // ---- phase 3: quad(1,0) ----
    BARRIER();
    __builtin_amdgcn_s_setprio(1);
    quad_mfma<1, 0>(af, bf, acc);
    __builtin_amdgcn_s_setprio(0);
}

__global__ __launch_bounds__(512, 2) void gemm256_kernel(
    const unsigned short* __restrict__ A, const unsigned short* __restrict__ B,
    const float* __restrict__ bias, float* __restrict__ C) {
    constexpr int K = C_CH, N = N_OUT;
    __shared__ alignas(128) char lds[131072];

    // XCD-bijective swizzle (nwg = 512, % 8 == 0)
    const int nwg = gridDim.x;
    const int cpx = nwg >> 3;
    int wg = blockIdx.x;
    wg = (wg & 7) * cpx + (wg >> 3);
    const int nbx = N >> 8;                 // 16
    const int bx = wg % nbx, by = wg / nbx;
    const int row0 = by << 8, col0 = bx << 8;

    const int t    = threadIdx.x;
    const int lane = t & 63;
    const int wid  = t >> 6;
    const int wm   = wid >> 2;              // 0..1
    const int wn   = wid & 3;               // 0..3
    const int l15  = lane & 15;
    const int lh   = lane >> 4;             // 0..3

    // staging source (pre-swizzled slot) and wave-uniform LDS dest
    const int sslot = (lane & 7) ^ (lane >> 3);
    const int dstw  = wid << 10;            // wid * 1024

    const char* pA0 = (const char*)A +
        ((size_t)(row0 + wid * 8 + (lane >> 3)) * K) * 2 + sslot * 16;
    const char* pA1 = pA0 + 1 * 64 * K * 2;
    const char* pA2 = pA0 + 2 * 64 * K * 2;
    const char* pA3 = pA0 + 3 * 64 * K * 2;
    const char* pB0 = (const char*)B +
        ((size_t)(col0 + wid * 8 + (lane >> 3)) * K) * 2 + sslot * 16;
    const char* pB1 = pB0 + 1 * 64 * K * 2;
    const char* pB2 = pB0 + 2 * 64 * K * 2;
    const char* pB3 = pB0 + 3 * 64 * K * 2;

    // fragment read offsets (T2 swizzle: slot ^ (row&7), row&7 == l15&7)
    const int x7 = l15 & 7;
    const int aoff0 = wm * 16384 + l15 * 128 + ((lh     ) ^ x7) * 16;
    const int aoff1 = wm * 16384 + l15 * 128 + ((lh +  4) ^ x7) * 16;
    const int boff0 = 32768 + (wn >> 1) * 16384 + (wn & 1) * 8192 + l15 * 128 + ((lh    ) ^ x7) * 16;
    const int boff1 = 32768 + (wn >> 1) * 16384 + (wn & 1) * 8192 + l15 * 128 + ((lh + 4) ^ x7) * 16;

    f32x4 acc[8][4];
    #pragma unroll
    for (int m = 0; m < 8; ++m)
        #pragma unroll
        for (int n = 0; n < 4; ++n)
            acc[m][n] = (f32x4){0.f, 0.f, 0.f, 0.f};

    // prologue: stage tile 0 into buf0
    gload16(pA0, lds +     0 + dstw);
    gload16(pA1, lds +  8192 + dstw);
    gload16(pA2, lds + 16384 + dstw);
    gload16(pA3, lds + 24576 + dstw);
    gload16(pB0, lds + 32768 + dstw);
    gload16(pB1, lds + 40960 + dstw);
    gload16(pB2, lds + 49152 + dstw);
    gload16(pB3, lds + 57344 + dstw);
    pA0 += 128; pA1 += 128; pA2 += 128; pA3 += 128;
    pB0 += 128; pB1 += 128; pB2 += 128; pB3 += 128;

    // 64 K-tiles: 31 double iterations + 2 tail tiles
    #pragma unroll 1
    for (int it = 0; it < 31; ++it) {
        tile_step<true >(lds,     0, 65536, pA0, pA1, pA2, pA3, pB0, pB1, pB2, pB3,
                         dstw, aoff0, aoff1, boff0, boff1, acc);
        tile_step<true >(lds, 65536,     0, pA0, pA1, pA2, pA3, pB0, pB1, pB2, pB3,
                         dstw, aoff0, aoff1, boff0, boff1, acc);
    }
    tile_step<true >(lds,     0, 65536, pA0, pA1, pA2, pA3, pB0, pB1, pB2, pB3,
                     dstw, aoff0, aoff1, boff0, boff1, acc);
    tile_step<false>(lds, 65536,     0, pA0, pA1, pA2, pA3, pB0, pB1, pB2, pB3,
                     dstw, aoff0, aoff1, boff0, boff1, acc);

    // epilogue: C[row][col] = acc + bias[col]
    const int crow0 = row0 + wm * 128 + lh * 4;
    const int ccol0 = col0 + wn * 64 + l15;
    #pragma unroll
    for (int n = 0; n < 4; ++n) {
        const float bv = bias[ccol0 + n * 16];
        #pragma unroll
        for (int m = 0; m < 8; ++m) {
            const size_t base = (size_t)(crow0 + m * 16) * N + (ccol0 + n * 16);
            #pragma unroll
            for (int j = 0; j < 4; ++j)
                C[base + (size_t)j * N] = acc[m][n][j] + bv;
        }
    }
}

// ---------------------- launch --------------------------------------------
extern "C" void kernel_launch(void* const* d_in, const int* in_sizes, int n_in,
                              void* d_out, int out_size, void* d_ws, size_t ws_size,
                              hipStream_t stream) {
    const float* x     = (const float*)d_in[0];
    const float* gamma = (const float*)d_in[1];
    const float* beta  = (const float*)d_in[2];
    const float* W     = (const float*)d_in[3];
    const float* b     = (const float*)d_in[4];
    float* out = (float*)d_out;

    char* ws = (char*)d_ws;
    unsigned short* Abf = (unsigned short*)(ws);                       // 64 MiB
    unsigned short* Wbf = (unsigned short*)(ws + 67108864);            // 32 MiB
    float* psum   = (float*)(ws + 100663296);                          // 8 MiB
    float* psumsq = (float*)(ws + 100663296 + 8388608);                // 8 MiB
    float* scale  = (float*)(ws + 100663296 + 16777216);               // 16 KiB
    float* shift  = (float*)(ws + 100663296 + 16777216 + 16384);       // 16 KiB

    hipLaunchKernelGGL(stats_kernel,    dim3(512),  dim3(256), 0, stream, x, psum, psumsq);
    hipLaunchKernelGGL(finalize_kernel, dim3(16),   dim3(256), 0, stream,
                       psum, psumsq, gamma, beta, scale, shift);
    hipLaunchKernelGGL(convA_kernel,    dim3(2048), dim3(256), 0, stream, x, scale, shift, Abf);
    hipLaunchKernelGGL(convW_kernel,    dim3(2048), dim3(256), 0, stream, W, Wbf);
    hipLaunchKernelGGL(gemm256_kernel,  dim3(512),  dim3(512), 0, stream,
                       Abf, Wbf, b, out);
}

// Round 3
// 365.936 us; speedup vs baseline: 1.4159x; 1.1210x over previous
//
#include <hip/hip_runtime.h>

// ---------------------------------------------------------------------------
// Problem: h = relu(x + noise); BN1d(train, eps=0.8); z = hn @ W^T + b
// x: [8192, 4096] f32, W: [4096, 4096] f32, out: [8192, 4096] f32
// ---------------------------------------------------------------------------

#define B_ROWS 8192
#define C_CH   4096
#define N_OUT  4096

// ---------------------- compile-time noise table --------------------------
struct alignas(16) NoiseTable { float v[C_CH]; };

constexpr NoiseTable make_noise() {
    unsigned s = 123u;
    unsigned pool[C_CH] = {};
    for (int i = 0; i < C_CH; ++i) { s = 65539u * s + 1u; pool[i] = s; }
    int nxt = C_CH - 1;
    NoiseTable t{};
    for (int i = 0; i < C_CH; ++i) {
        nxt = (int)(pool[nxt] % (unsigned)C_CH);
        t.v[i] = (float)((double)pool[nxt] * 1e-9);
        s = 65539u * s + 1u;
        pool[nxt] = s;
    }
    return t;
}

__device__ constexpr NoiseTable NOISE = make_noise();

// ---------------------- helpers -------------------------------------------
__device__ __forceinline__ unsigned short f2bf(float f) {
    unsigned u = __builtin_bit_cast(unsigned, f);
    unsigned r = (u + 0x7FFFu + ((u >> 16) & 1u)) >> 16;   // RNE
    return (unsigned short)r;
}

typedef __attribute__((ext_vector_type(8))) short bf16x8;
typedef __attribute__((ext_vector_type(4))) float f32x4;

__device__ __forceinline__ void gload16(const void* g, void* l) {
    __builtin_amdgcn_global_load_lds(
        (const __attribute__((address_space(1))) void*)g,
        (__attribute__((address_space(3))) void*)l, 16, 0, 0);
}

#define BARRIER()  do { __builtin_amdgcn_s_barrier(); asm volatile("" ::: "memory"); } while (0)
#define LGKM0()    do { asm volatile("s_waitcnt lgkmcnt(0)" ::: "memory"); \
                        __builtin_amdgcn_sched_barrier(0); } while (0)

// ---------------------- 1) BN stats: per-block partial sums ----------------
__global__ __launch_bounds__(256) void stats_kernel(const float* __restrict__ x,
                                                    float* __restrict__ psum,
                                                    float* __restrict__ psumsq) {
    const int t = threadIdx.x;
    const int b = blockIdx.x;

    float4 nv[4];
    #pragma unroll
    for (int g = 0; g < 4; ++g)
        nv[g] = *reinterpret_cast<const float4*>(&NOISE.v[g * 1024 + 4 * t]);

    float4 s[4], q[4];
    #pragma unroll
    for (int g = 0; g < 4; ++g) { s[g] = make_float4(0,0,0,0); q[g] = make_float4(0,0,0,0); }

    const int row0 = b * 16;
    for (int r = 0; r < 16; ++r) {
        const float* xr = x + (size_t)(row0 + r) * C_CH;
        #pragma unroll
        for (int g = 0; g < 4; ++g) {
            float4 v = *reinterpret_cast<const float4*>(&xr[g * 1024 + 4 * t]);
            float h0 = fmaxf(v.x + nv[g].x, 0.f);
            float h1 = fmaxf(v.y + nv[g].y, 0.f);
            float h2 = fmaxf(v.z + nv[g].z, 0.f);
            float h3 = fmaxf(v.w + nv[g].w, 0.f);
            s[g].x += h0; s[g].y += h1; s[g].z += h2; s[g].w += h3;
            q[g].x += h0*h0; q[g].y += h1*h1; q[g].z += h2*h2; q[g].w += h3*h3;
        }
    }
    #pragma unroll
    for (int g = 0; g < 4; ++g) {
        *reinterpret_cast<float4*>(&psum  [(size_t)b * C_CH + g * 1024 + 4 * t]) = s[g];
        *reinterpret_cast<float4*>(&psumsq[(size_t)b * C_CH + g * 1024 + 4 * t]) = q[g];
    }
}

// ---------------------- 2) finalize: scale/shift per channel ---------------
__global__ __launch_bounds__(256) void finalize_kernel(const float* __restrict__ psum,
                                                       const float* __restrict__ psumsq,
                                                       const float* __restrict__ gamma,
                                                       const float* __restrict__ beta,
                                                       float* __restrict__ scale,
                                                       float* __restrict__ shift) {
    const int c = blockIdx.x * 256 + threadIdx.x;
    float s = 0.f, q = 0.f;
    for (int bk = 0; bk < 512; ++bk) {
        s += psum  [(size_t)bk * C_CH + c];
        q += psumsq[(size_t)bk * C_CH + c];
    }
    const float inv = 1.f / (float)B_ROWS;
    const float mean = s * inv;
    const float var  = fmaxf(q * inv - mean * mean, 0.f);
    const float sc   = gamma[c] / sqrtf(var + 0.8f);
    scale[c] = sc;
    shift[c] = beta[c] - mean * sc;
}

// ---------------------- 3) A conversion: hn in bf16 ------------------------
__global__ __launch_bounds__(256) void convA_kernel(const float* __restrict__ x,
                                                    const float* __restrict__ scale,
                                                    const float* __restrict__ shift,
                                                    unsigned short* __restrict__ out) {
    const size_t total4 = (size_t)B_ROWS * C_CH / 4;
    for (size_t i = (size_t)blockIdx.x * 256 + threadIdx.x; i < total4;
         i += (size_t)gridDim.x * 256) {
        const size_t e = i * 4;
        const int c = (int)(e & (C_CH - 1));
        float4 v  = *reinterpret_cast<const float4*>(&x[e]);
        float4 nv = *reinterpret_cast<const float4*>(&NOISE.v[c]);
        float4 sc = *reinterpret_cast<const float4*>(&scale[c]);
        float4 sh = *reinterpret_cast<const float4*>(&shift[c]);
        ushort4 o;
        o.x = f2bf(fmaxf(v.x + nv.x, 0.f) * sc.x + sh.x);
        o.y = f2bf(fmaxf(v.y + nv.y, 0.f) * sc.y + sh.y);
        o.z = f2bf(fmaxf(v.z + nv.z, 0.f) * sc.z + sh.z);
        o.w = f2bf(fmaxf(v.w + nv.w, 0.f) * sc.w + sh.w);
        *reinterpret_cast<ushort4*>(&out[e]) = o;
    }
}

// ---------------------- 4) W conversion to bf16 ----------------------------
__global__ __launch_bounds__(256) void convW_kernel(const float* __restrict__ W,
                                                    unsigned short* __restrict__ out) {
    const size_t total4 = (size_t)N_OUT * C_CH / 4;
    for (size_t i = (size_t)blockIdx.x * 256 + threadIdx.x; i < total4;
         i += (size_t)gridDim.x * 256) {
        const size_t e = i * 4;
        float4 v = *reinterpret_cast<const float4*>(&W[e]);
        ushort4 o;
        o.x = f2bf(v.x); o.y = f2bf(v.y); o.z = f2bf(v.z); o.w = f2bf(v.w);
        *reinterpret_cast<ushort4*>(&out[e]) = o;
    }
}

// ---------------------- 5) GEMM 256x256x64, 8 waves, fine interleave -------
// LDS buffer (65536 B): A [256 rows][64 k] at +0 in 4 chunks of 64 rows
// (A0@0, A1@8192, A2@16384, A3@24576); B likewise at +32768 (B0..B3).
// T2 swizzle: within a row (8 x 16B slots) stored slot = slot ^ (row&7);
// global_load_lds writes linearly, SOURCE is pre-swizzled (both-sides rule).
//
// Per K-tile, 4 phases (quadrants), chunk needs: ph0 {B0-3,A0,A2}, ph2 {A1,A3}.
// Stage order for tile t+1: ph0 {B0,B1}, ph1 {B2,B3}, ph2 {A0,A2}, ph3 {A1,A3}
// -> per-wave outstanding bookkeeping gives vmcnt(2)@ph0, vmcnt(4)@ph2.
// 2 barriers/K-tile, each right after its counted vmcnt (block-wide landing +
// double-buffer reuse fence). Never vmcnt(0) except the tail tile.

template<int MH, int NH>
__device__ __forceinline__ void quad_mfma(bf16x8 (&af)[4][2], bf16x8 (&bf)[4][2],
                                          f32x4 (&acc)[8][4]) {
    #pragma unroll
    for (int s = 0; s < 2; ++s)
        #pragma unroll
        for (int m = 0; m < 4; ++m)
            #pragma unroll
            for (int n = 0; n < 2; ++n)
                acc[MH * 4 + m][NH * 2 + n] = __builtin_amdgcn_mfma_f32_16x16x32_bf16(
                    af[m][s], bf[NH * 2 + n][s], acc[MH * 4 + m][NH * 2 + n], 0, 0, 0);
}

template<bool STG>
__device__ __forceinline__ void tile_step(
    char* lds, const int bc, const int bn,
    const char*& pA0, const char*& pA1, const char*& pA2, const char*& pA3,
    const char*& pB0, const char*& pB1, const char*& pB2, const char*& pB3,
    const int dstw, const int aoff0, const int aoff1,
    const int boff0, const int boff1,
    f32x4 (&acc)[8][4]) {

    bf16x8 af[4][2], bf[4][2];

    // ======== phase 0: quad(m0-3, n0-1); needs B0-3,A0,A2 (6 oldest) ========
    asm volatile("s_waitcnt vmcnt(2)" ::: "memory");
    BARRIER();                       // block-wide landing + bn reuse fence
    __builtin_amdgcn_sched_barrier(0);
    if (STG) {
        gload16(pB0, lds + bn + 32768 + dstw);
        gload16(pB1, lds + bn + 40960 + dstw);
    }
    #pragma unroll
    for (int m = 0; m < 4; ++m) {
        af[m][0] = *reinterpret_cast<const bf16x8*>(lds + bc + aoff0 + m * 2048);
        af[m][1] = *reinterpret_cast<const bf16x8*>(lds + bc + aoff1 + m * 2048);
    }
    #pragma unroll
    for (int n = 0; n < 2; ++n) {
        bf[n][0] = *reinterpret_cast<const bf16x8*>(lds + bc + boff0 + n * 2048);
        bf[n][1] = *reinterpret_cast<const bf16x8*>(lds + bc + boff1 + n * 2048);
    }
    LGKM0();
    __builtin_amdgcn_s_setprio(1);
    quad_mfma<0, 0>(af, bf, acc);
    __builtin_amdgcn_s_setprio(0);

    // ======== phase 1: quad(m0-3, n2-3); B chunks already resident ========
    if (STG) {
        gload16(pB2, lds + bn + 49152 + dstw);
        gload16(pB3, lds + bn + 57344 + dstw);
    }
    #pragma unroll
    for (int n = 2; n < 4; ++n) {
        bf[n][0] = *reinterpret_cast<const bf16x8*>(lds + bc + boff0 + n * 2048);
        bf[n][1] = *reinterpret_cast<const bf16x8*>(lds + bc + boff1 + n * 2048);
    }
    LGKM0();
    __builtin_amdgcn_s_setprio(1);
    quad_mfma<0, 1>(af, bf, acc);
    __builtin_amdgcn_s_setprio(0);

    // ======== phase 2: quad(m4-7, n2-3); needs A1,A3 (2 oldest) ========
    if (STG) asm volatile("s_waitcnt vmcnt(4)" ::: "memory");
    else     asm volatile("s_waitcnt vmcnt(0)" ::: "memory");
    BARRIER();
    __builtin_amdgcn_sched_barrier(0);
    if (STG) {
        gload16(pA0, lds + bn +     0 + dstw);
        gload16(pA2, lds + bn + 16384 + dstw);
    }
    #pragma unroll
    for (int m = 0; m < 4; ++m) {
        af[m][0] = *reinterpret_cast<const bf16x8*>(lds + bc + aoff0 + (m + 4) * 2048);
        af[m][1] = *reinterpret_cast<const bf16x8*>(lds + bc + aoff1 + (m + 4) * 2048);
    }
    LGKM0();
    __builtin_amdgcn_s_setprio(1);
    quad_mfma<1, 1>(af, bf, acc);
    __builtin_amdgcn_s_setprio(0);

    // ======== phase 3: quad(m4-7, n0-1); pure register phase ========
    if (STG) {
        gload16(pA1, lds + bn +  8192 + dstw);
        gload16(pA3, lds + bn + 24576 + dstw);
        pA0 += 128; pA1 += 128; pA2 += 128; pA3 += 128;
        pB0 += 128; pB1 += 128; pB2 += 128; pB3 += 128;
    }
    __builtin_amdgcn_s_setprio(1);
    quad_mfma<1, 0>(af, bf, acc);
    __builtin_amdgcn_s_setprio(0);
}

__global__ __launch_bounds__(512, 2) void gemm256_kernel(
    const unsigned short* __restrict__ A, const unsigned short* __restrict__ B,
    const float* __restrict__ bias, float* __restrict__ C) {
    constexpr int K = C_CH, N = N_OUT;
    __shared__ alignas(128) char lds[131072];

    // XCD-bijective swizzle (nwg = 512, % 8 == 0)
    const int nwg = gridDim.x;
    const int cpx = nwg >> 3;
    int wg = blockIdx.x;
    wg = (wg & 7) * cpx + (wg >> 3);
    const int nbx = N >> 8;                 // 16
    const int bx = wg % nbx, by = wg / nbx;
    const int row0 = by << 8, col0 = bx << 8;

    const int t    = threadIdx.x;
    const int lane = t & 63;
    const int wid  = t >> 6;
    const int wm   = wid >> 2;              // 0..1
    const int wn   = wid & 3;               // 0..3
    const int l15  = lane & 15;
    const int lh   = lane >> 4;             // 0..3

    // staging source (pre-swizzled slot) and wave-uniform LDS dest
    const int sslot = (lane & 7) ^ (lane >> 3);
    const int dstw  = wid << 10;            // wid * 1024

    const char* pA0 = (const char*)A +
        ((size_t)(row0 + wid * 8 + (lane >> 3)) * K) * 2 + sslot * 16;
    const char* pA1 = pA0 + 1 * 64 * K * 2;
    const char* pA2 = pA0 + 2 * 64 * K * 2;
    const char* pA3 = pA0 + 3 * 64 * K * 2;
    const char* pB0 = (const char*)B +
        ((size_t)(col0 + wid * 8 + (lane >> 3)) * K) * 2 + sslot * 16;
    const char* pB1 = pB0 + 1 * 64 * K * 2;
    const char* pB2 = pB0 + 2 * 64 * K * 2;
    const char* pB3 = pB0 + 3 * 64 * K * 2;

    // fragment read offsets (T2 swizzle: slot ^ (row&7), row&7 == l15&7)
    const int x7 = l15 & 7;
    const int aoff0 = wm * 16384 + l15 * 128 + ((lh     ) ^ x7) * 16;
    const int aoff1 = wm * 16384 + l15 * 128 + ((lh +  4) ^ x7) * 16;
    const int boff0 = 32768 + wn * 8192 + l15 * 128 + ((lh    ) ^ x7) * 16;
    const int boff1 = 32768 + wn * 8192 + l15 * 128 + ((lh + 4) ^ x7) * 16;

    f32x4 acc[8][4];
    #pragma unroll
    for (int m = 0; m < 8; ++m)
        #pragma unroll
        for (int n = 0; n < 4; ++n)
            acc[m][n] = (f32x4){0.f, 0.f, 0.f, 0.f};

    // prologue: stage tile 0 into buf0 in vmcnt-matched order
    // (B0,B1,B2,B3,A0,A2 = oldest 6; A1,A3 = newest 2)
    gload16(pB0, lds + 32768 + dstw);
    gload16(pB1, lds + 40960 + dstw);
    gload16(pB2, lds + 49152 + dstw);
    gload16(pB3, lds + 57344 + dstw);
    gload16(pA0, lds +     0 + dstw);
    gload16(pA2, lds + 16384 + dstw);
    gload16(pA1, lds +  8192 + dstw);
    gload16(pA3, lds + 24576 + dstw);
    pA0 += 128; pA1 += 128; pA2 += 128; pA3 += 128;
    pB0 += 128; pB1 += 128; pB2 += 128; pB3 += 128;

    // 64 K-tiles: 31 double iterations + staged tile + tail tile
    #pragma unroll 1
    for (int it = 0; it < 31; ++it) {
        tile_step<true >(lds,     0, 65536, pA0, pA1, pA2, pA3, pB0, pB1, pB2, pB3,
                         dstw, aoff0, aoff1, boff0, boff1, acc);
        tile_step<true >(lds, 65536,     0, pA0, pA1, pA2, pA3, pB0, pB1, pB2, pB3,
                         dstw, aoff0, aoff1, boff0, boff1, acc);
    }
    tile_step<true >(lds,     0, 65536, pA0, pA1, pA2, pA3, pB0, pB1, pB2, pB3,
                     dstw, aoff0, aoff1, boff0, boff1, acc);
    tile_step<false>(lds, 65536,     0, pA0, pA1, pA2, pA3, pB0, pB1, pB2, pB3,
                     dstw, aoff0, aoff1, boff0, boff1, acc);

    // epilogue: C[row][col] = acc + bias[col]
    const int crow0 = row0 + wm * 128 + lh * 4;
    const int ccol0 = col0 + wn * 64 + l15;
    #pragma unroll
    for (int n = 0; n < 4; ++n) {
        const float bv = bias[ccol0 + n * 16];
        #pragma unroll
        for (int m = 0; m < 8; ++m) {
            const size_t base = (size_t)(crow0 + m * 16) * N + (ccol0 + n * 16);
            #pragma unroll
            for (int j = 0; j < 4; ++j)
                C[base + (size_t)j * N] = acc[m][n][j] + bv;
        }
    }
}

// ---------------------- launch --------------------------------------------
extern "C" void kernel_launch(void* const* d_in, const int* in_sizes, int n_in,
                              void* d_out, int out_size, void* d_ws, size_t ws_size,
                              hipStream_t stream) {
    const float* x     = (const float*)d_in[0];
    const float* gamma = (const float*)d_in[1];
    const float* beta  = (const float*)d_in[2];
    const float* W     = (const float*)d_in[3];
    const float* b     = (const float*)d_in[4];
    float* out = (float*)d_out;

    char* ws = (char*)d_ws;
    unsigned short* Abf = (unsigned short*)(ws);                       // 64 MiB
    unsigned short* Wbf = (unsigned short*)(ws + 67108864);            // 32 MiB
    float* psum   = (float*)(ws + 100663296);                          // 8 MiB
    float* psumsq = (float*)(ws + 100663296 + 8388608);                // 8 MiB
    float* scale  = (float*)(ws + 100663296 + 16777216);               // 16 KiB
    float* shift  = (float*)(ws + 100663296 + 16777216 + 16384);       // 16 KiB

    hipLaunchKernelGGL(stats_kernel,    dim3(512),  dim3(256), 0, stream, x, psum, psumsq);
    hipLaunchKernelGGL(finalize_kernel, dim3(16),   dim3(256), 0, stream,
                       psum, psumsq, gamma, beta, scale, shift);
    hipLaunchKernelGGL(convA_kernel,    dim3(2048), dim3(256), 0, stream, x, scale, shift, Abf);
    hipLaunchKernelGGL(convW_kernel,    dim3(2048), dim3(256), 0, stream, W, Wbf);
    hipLaunchKernelGGL(gemm256_kernel,  dim3(512),  dim3(512), 0, stream,
                       Abf, Wbf, b, out);
}